// Round 6
// baseline (109.048 us; speedup 1.0000x reference)
//
#include <hip/hip_runtime.h>

#define INF_BITS 0x7F800000u
#define AS1 __attribute__((address_space(1)))
#define AS3 __attribute__((address_space(3)))

typedef float f32x4 __attribute__((ext_vector_type(4)));
typedef __bf16 bf16x8 __attribute__((ext_vector_type(8)));
typedef unsigned short u16x8 __attribute__((ext_vector_type(8)));
typedef unsigned int u32x4 __attribute__((ext_vector_type(4)));

static __device__ __forceinline__ unsigned short f2bf(float f) {
  unsigned int u = __float_as_uint(f);
  return (unsigned short)((u + 0x7FFFu + ((u >> 16) & 1u)) >> 16);  // RTNE
}

// ---- init: +inf min-dists; zero xT pad rows; +inf x2 pad ----
__global__ void k_init(unsigned int* __restrict__ outu, u32x4* __restrict__ xTpad,
                       unsigned int* __restrict__ x2u) {
  int i = blockIdx.x * blockDim.x + threadIdx.x;
  if (i < 64000) outu[6400 + i] = INF_BITS;
  if (i < 32768) xTpad[i] = (u32x4){0u, 0u, 0u, 0u};  // rows 6272..6399 of xT
  if (i < 128) x2u[6272 + i] = INF_BITS;
}

// ---- protos (2000x2048 f32) -> pT (2048x2048 bf16, pad rows zero) + p2 ----
__global__ __launch_bounds__(256) void k_prep_p(const float* __restrict__ protos,
                                                unsigned short* __restrict__ pT,
                                                float* __restrict__ p2) {
  const int row = blockIdx.x;   // 2048
  const int tid = threadIdx.x;  // 256
  __shared__ float red[4];
  float s = 0.f;
  u16x8 h = (u16x8){0, 0, 0, 0, 0, 0, 0, 0};
  if (row < 2000) {
    const float* src = protos + (size_t)row * 2048 + tid * 8;
    f32x4 a = *(const f32x4*)src;
    f32x4 c = *(const f32x4*)(src + 4);
    h = (u16x8){f2bf(a.x), f2bf(a.y), f2bf(a.z), f2bf(a.w),
                f2bf(c.x), f2bf(c.y), f2bf(c.z), f2bf(c.w)};
    s = a.x * a.x + a.y * a.y + a.z * a.z + a.w * a.w +
        c.x * c.x + c.y * c.y + c.z * c.z + c.w * c.w;
  }
  *(u16x8*)(pT + (size_t)row * 2048 + tid * 8) = h;
  #pragma unroll
  for (int off = 32; off; off >>= 1) s += __shfl_xor(s, off);
  if ((tid & 63) == 0) red[tid >> 6] = s;
  __syncthreads();
  if (tid == 0) p2[row] = red[0] + red[1] + red[2] + red[3];
}

// ---- x (b,k,n) f32 -> xT[(b*196+n)*2048+k] bf16 + x2 partials ----
__global__ __launch_bounds__(256) void k_prep_x(const float* __restrict__ x,
                                                unsigned short* __restrict__ xT,
                                                float* __restrict__ x2p) {
  const int kt = blockIdx.x;  // 32
  const int b  = blockIdx.y;  // 32
  const int tid = threadIdx.x;
  __shared__ unsigned short Ls[64][201];
  const float* src = x + ((size_t)b * 2048 + (size_t)kt * 64) * 196;
  for (int idx = tid; idx < 64 * 196; idx += 256) {
    int kk = idx / 196, n = idx - kk * 196;
    Ls[kk][n] = f2bf(src[idx]);
  }
  __syncthreads();
  if (tid < 196) {  // x2 partial from bf16 values (column tid)
    float s = 0.f;
    #pragma unroll
    for (int j = 0; j < 64; ++j) {
      float v = __uint_as_float((unsigned int)Ls[j][tid] << 16);
      s += v * v;
    }
    x2p[kt * 6272 + b * 196 + tid] = s;
  }
  unsigned short* dstb = xT + (size_t)b * 196 * 2048 + kt * 64;
  for (int idx = tid; idx < 196 * 32; idx += 256) {
    int n = idx >> 5, j = idx & 31;
    unsigned int v = (unsigned int)Ls[2 * j][n] |
                     ((unsigned int)Ls[2 * j + 1][n] << 16);
    *(unsigned int*)(dstb + (size_t)n * 2048 + 2 * j) = v;
  }
}

__global__ void k_x2r(const float* __restrict__ x2p, float* __restrict__ x2) {
  int i = blockIdx.x * blockDim.x + threadIdx.x;
  if (i >= 6272) return;
  float s = 0.f;
  #pragma unroll
  for (int c = 0; c < 32; ++c) s += x2p[c * 6272 + i];
  x2[i] = s;
}

// ---- main GEMM: 256x256 tile, BK=64, 8 waves, 2-phase/K-tile (4 barriers) ----
__global__ __launch_bounds__(512, 2) void k_main(
    const unsigned short* __restrict__ pT, const unsigned short* __restrict__ xT,
    const float* __restrict__ p2, const float* __restrict__ x2,
    unsigned int* __restrict__ outu) {
  // XCD swizzle: XCD x owns wgid [25x, 25x+25) = 2 ptiles x ~12.5 mtiles
  const int orig = blockIdx.x;
  const int wgid = (orig & 7) * 25 + (orig >> 3);
  const int ptpair = wgid / 50;
  const int rem = wgid - ptpair * 50;
  const int ptile = ptpair * 2 + (rem & 1);  // 0..7
  const int mtile = rem >> 1;                // 0..24
  const int p0 = ptile * 256;
  const int m0 = mtile * 256;
  const int tid = threadIdx.x;
  const int lane = tid & 63;
  const int w = tid >> 6;   // 8 waves
  const int wp = w >> 2;    // A half (128 rows)
  const int wn = w & 3;     // B quarter (64 rows)
  const int lr = lane & 15;
  const int lg = lane >> 4;

  __shared__ __align__(16) char S[131072];  // A[2]:0..64K, B[2]:64K..128K

  f32x4 acc[8][4];
  #pragma unroll
  for (int mi = 0; mi < 8; ++mi)
    #pragma unroll
    for (int ni = 0; ni < 4; ++ni)
      acc[mi][ni] = (f32x4){0.f, 0.f, 0.f, 0.f};

  // staging: linear LDS dest, pre-swizzled global source (chunk ^= row&7)
  const int rowbase = tid >> 3;                       // 0..63
  const int chunk = (tid & 7) ^ (rowbase & 7);        // involution
  const char* gA = (const char*)pT + (size_t)(p0 + rowbase) * 4096 + chunk * 16;
  const char* gB = (const char*)xT + (size_t)(m0 + rowbase) * 4096 + chunk * 16;
  const int wbase = w * 1024;

#define STAGE_A(c_, kt_, h_) do {                                              \
    const char* s_ = gA + (size_t)((h_) * 128 * 4096) + (size_t)(kt_) * 128;   \
    _Pragma("unroll")                                                          \
    for (int j_ = 0; j_ < 2; ++j_)                                             \
      __builtin_amdgcn_global_load_lds(                                        \
          (const AS1 void*)(s_ + (size_t)j_ * 64 * 4096),                      \
          (AS3 void*)(S + (c_) * 32768 + (h_) * 16384 + j_ * 8192 + wbase),    \
          16, 0, 0);                                                           \
  } while (0)
#define STAGE_B(c_, kt_, h_) do {                                              \
    const char* s_ = gB + (size_t)((h_) * 128 * 4096) + (size_t)(kt_) * 128;   \
    _Pragma("unroll")                                                          \
    for (int j_ = 0; j_ < 2; ++j_)                                             \
      __builtin_amdgcn_global_load_lds(                                        \
          (const AS1 void*)(s_ + (size_t)j_ * 64 * 4096),                      \
          (AS3 void*)(S + 65536 + (c_) * 32768 + (h_) * 16384 + j_ * 8192 + wbase), \
          16, 0, 0);                                                           \
  } while (0)

  // ds_read fragment addressing (row&7 == lr&7 since all row steps are x16)
  const int swz = ((lr & 7) << 4);
  const int arow = (wp * 128 + lr) * 128;        // + (mi>>2)*8192 + (mi&3)*2048
  const int brow = (wn * 64 + lr) * 128;         // + ni*2048 (B region +65536)
  const int koff0 = (lg * 16) ^ swz;
  const int koff1 = (64 + lg * 16) ^ swz;

#define READ_A8(dst_, c_, ko_)                                                 \
    _Pragma("unroll")                                                          \
    for (int mi_ = 0; mi_ < 8; ++mi_)                                          \
      dst_[mi_] = *(const bf16x8*)(S + (c_) * 32768 + arow + (mi_ >> 2) * 8192 \
                                   + (mi_ & 3) * 2048 + (ko_));
#define READ_B(dst_, c_, ko_)                                                  \
    _Pragma("unroll")                                                          \
    for (int ni_ = 0; ni_ < 4; ++ni_)                                          \
      dst_[ni_] = *(const bf16x8*)(S + 65536 + (c_) * 32768 + brow +           \
                                   ni_ * 2048 + (ko_));

#define PH_BAR() do { __builtin_amdgcn_sched_barrier(0);                       \
    __builtin_amdgcn_s_barrier(); __builtin_amdgcn_sched_barrier(0); } while (0)
#define LGKM0() do { asm volatile("s_waitcnt lgkmcnt(0)" ::: "memory");        \
    __builtin_amdgcn_sched_barrier(0); } while (0)
#define MFMA_ALL(af_, bf_) do { __builtin_amdgcn_s_setprio(1);                 \
    _Pragma("unroll")                                                          \
    for (int mi_ = 0; mi_ < 8; ++mi_)                                          \
      _Pragma("unroll")                                                        \
      for (int ni_ = 0; ni_ < 4; ++ni_)                                        \
        acc[mi_][ni_] = __builtin_amdgcn_mfma_f32_16x16x32_bf16(               \
            af_[mi_], bf_[ni_], acc[mi_][ni_], 0, 0, 0);                       \
    __builtin_amdgcn_s_setprio(0); } while (0)

  // Per K-tile kt (buf c): 2 phases.
  //  Ph0: read A[c]kh0(8)+B[c]kh0(4); stage A[kt+1]->buf c^1; bar; lgkm0;
  //       32 MFMA; bar.
  //  Ph1: read A[c]kh1(8)+B[c]kh1(4); bar; lgkm0; 32 MFMA; vmcnt(0) retiring
  //       {B[kt+1],A[kt+1]} (>=1.5-phase cover); bar; stage B[kt+2]->buf c
  //       (structural: all B[c] readers passed lgkm0 before that bar).
#define KT_BODY(kt_, c_, sa_, sb_, vm_) do {                                   \
    bf16x8 a8[8], bb[4];                                                       \
    READ_A8(a8, c_, koff0);                                                    \
    READ_B(bb, c_, koff0);                                                     \
    if (sa_) { STAGE_A((c_) ^ 1, (kt_) + 1, 0); STAGE_A((c_) ^ 1, (kt_) + 1, 1); } \
    PH_BAR(); LGKM0();                                                         \
    MFMA_ALL(a8, bb);                                                          \
    PH_BAR();                                                                  \
    READ_A8(a8, c_, koff1);                                                    \
    READ_B(bb, c_, koff1);                                                     \
    PH_BAR(); LGKM0();                                                         \
    MFMA_ALL(a8, bb);                                                          \
    if ((vm_) == 0) { asm volatile("s_waitcnt vmcnt(0)" ::: "memory");         \
      __builtin_amdgcn_sched_barrier(0); }                                     \
    PH_BAR();                                                                  \
    if (sb_) { STAGE_B(c_, (kt_) + 2, 0); STAGE_B(c_, (kt_) + 2, 1); }         \
  } while (0)

  // prologue: A[0],B[0] -> buf0 ; B[1] -> buf1 ; retire A0+B0, keep B1 flying
  STAGE_A(0, 0, 0); STAGE_A(0, 0, 1);
  STAGE_B(0, 0, 0); STAGE_B(0, 0, 1);
  STAGE_B(1, 1, 0); STAGE_B(1, 1, 1);
  asm volatile("s_waitcnt vmcnt(4)" ::: "memory");
  __builtin_amdgcn_sched_barrier(0);
  __builtin_amdgcn_s_barrier();
  __builtin_amdgcn_sched_barrier(0);

  #pragma unroll 1
  for (int it = 0; it < 15; ++it) {
    KT_BODY(2 * it, 0, 1, 1, 0);
    KT_BODY(2 * it + 1, 1, 1, 1, 0);
  }
  KT_BODY(30, 0, 1, 0, 0);   // stages A[31]; no B[32]; drains all
  KT_BODY(31, 1, 0, 0, -1);  // pure compute
#undef KT_BODY
#undef MFMA_ALL
#undef READ_A8
#undef READ_B
#undef STAGE_A
#undef STAGE_B

  // epilogue: d2 = x2[m] + p2[p] - 2*dot ; per-wave 64-col window, <=2 batches
  const int wm_base = m0 + wn * 64;
  const int b_lo = wm_base / 196;
  int b_hi = (wm_base + 63) / 196;
  if (b_hi > 31) b_hi = 31;
  const bool wave_ok = (b_lo < 32);
  float x2v[4];
  int seg0[4];
  #pragma unroll
  for (int ni = 0; ni < 4; ++ni) {
    const int m = wm_base + ni * 16 + lr;  // D col = lane&15
    x2v[ni] = x2[m];
    seg0[ni] = ((m / 196) == b_lo);
  }
  const float INF = __uint_as_float(INF_BITS);
  #pragma unroll
  for (int mi = 0; mi < 8; ++mi) {
    const int prow = p0 + wp * 128 + mi * 16 + 4 * lg;  // D row = 4*(lane>>4)+j
    #pragma unroll
    for (int j = 0; j < 4; ++j) {
      const int p = prow + j;
      const float pp = p2[p];
      float ma = INF, mb = INF;
      #pragma unroll
      for (int ni = 0; ni < 4; ++ni) {
        const float d2 = x2v[ni] + pp - 2.f * acc[mi][ni][j];
        ma = fminf(ma, seg0[ni] ? d2 : INF);
        mb = fminf(mb, seg0[ni] ? INF : d2);
      }
      #pragma unroll
      for (int off = 1; off < 16; off <<= 1) {
        ma = fminf(ma, __shfl_xor(ma, off));
        mb = fminf(mb, __shfl_xor(mb, off));
      }
      if (lr == 0 && p < 2000 && wave_ok) {
        atomicMin(&outu[6400 + b_lo * 2000 + p], __float_as_uint(fmaxf(ma, 0.f)));
        if (b_hi != b_lo)
          atomicMin(&outu[6400 + b_hi * 2000 + p], __float_as_uint(fmaxf(mb, 0.f)));
      }
    }
  }
}

// ---- post: d = sqrt(max(d2,1e-12)) in place; sim -> simbuf ----
__global__ void k_post(float* __restrict__ out, float* __restrict__ simbuf) {
  int i = blockIdx.x * blockDim.x + threadIdx.x;
  if (i >= 64000) return;
  float d2 = out[6400 + i];
  float d = sqrtf(fmaxf(d2, 1e-12f));
  out[6400 + i] = d;
  simbuf[i] = logf((d + 1.0f) / (d + 1e-7f));
}

// ---- scores: one wave per (b, class) pair ----
__global__ __launch_bounds__(256) void k_scores(const float* __restrict__ fc_w,
                                                const float* __restrict__ simbuf,
                                                float* __restrict__ out) {
  const int id = blockIdx.x * 4 + (threadIdx.x >> 6);  // 0..6399
  const int lane = threadIdx.x & 63;
  const int b = id / 200;
  const int c = id - b * 200;
  const f32x4* sv = (const f32x4*)(simbuf + (size_t)b * 2000);
  const f32x4* wv = (const f32x4*)(fc_w + (size_t)c * 2000);
  float s = 0.f;
  #pragma unroll
  for (int it = 0; it < 8; ++it) {
    int i = lane + it * 64;
    if (i < 500) {
      f32x4 a = sv[i], w4 = wv[i];
      s += a.x * w4.x + a.y * w4.y + a.z * w4.z + a.w * w4.w;
    }
  }
  #pragma unroll
  for (int off = 32; off; off >>= 1) s += __shfl_xor(s, off);
  if (lane == 0) out[b * 200 + c] = s;
}

extern "C" void kernel_launch(void* const* d_in, const int* in_sizes, int n_in,
                              void* d_out, int out_size, void* d_ws, size_t ws_size,
                              hipStream_t stream) {
  const float* x      = (const float*)d_in[0];  // (32, 2048, 14, 14) f32
  const float* protos = (const float*)d_in[1];  // (1, 2000, 2048) f32
  const float* fc_w   = (const float*)d_in[2];  // (200, 2000) f32
  float* out = (float*)d_out;                   // 6400 scores + 64000 min-dists

  char* wsb = (char*)d_ws;
  unsigned short* pT = (unsigned short*)wsb;              // 2048*4096B  = 8388608
  unsigned short* xT = (unsigned short*)(wsb + 8388608);  // 6400*4096B  = 26214400
  float* p2   = (float*)(wsb + 34603008);                 // 2048 f32
  float* x2   = (float*)(wsb + 34611200);                 // 6400 f32 (pad +inf)
  float* x2p  = (float*)(wsb + 34636800);                 // 32*6272 f32
  float* simb = (float*)(wsb + 34636800);                 // aliases x2p (used later)

  k_init<<<256, 256, 0, stream>>>((unsigned int*)d_out,
                                  (u32x4*)(wsb + 8388608 + (size_t)6272 * 4096),
                                  (unsigned int*)x2);
  k_prep_p<<<2048, 256, 0, stream>>>(protos, pT, p2);
  k_prep_x<<<dim3(32, 32), 256, 0, stream>>>(x, xT, x2p);
  k_x2r<<<25, 256, 0, stream>>>(x2p, x2);
  k_main<<<200, 512, 0, stream>>>(pT, xT, p2, x2, (unsigned int*)d_out);
  k_post<<<250, 256, 0, stream>>>(out, simb);
  k_scores<<<1600, 256, 0, stream>>>(fc_w, simb, out);
}

// Round 7
// 108.961 us; speedup vs baseline: 1.0008x; 1.0008x over previous
//
#include <hip/hip_runtime.h>

#define INF_BITS 0x7F800000u
#define AS1 __attribute__((address_space(1)))
#define AS3 __attribute__((address_space(3)))

typedef float f32x4 __attribute__((ext_vector_type(4)));
typedef __bf16 bf16x8 __attribute__((ext_vector_type(8)));
typedef unsigned short u16x8 __attribute__((ext_vector_type(8)));
typedef unsigned int u32x4 __attribute__((ext_vector_type(4)));

static __device__ __forceinline__ unsigned short f2bf(float f) {
  unsigned int u = __float_as_uint(f);
  return (unsigned short)((u + 0x7FFFu + ((u >> 16) & 1u)) >> 16);  // RTNE
}

// ---- init: +inf min-dists; zero xT pad rows; +inf x2 pad ----
__global__ void k_init(unsigned int* __restrict__ outu, u32x4* __restrict__ xTpad,
                       unsigned int* __restrict__ x2u) {
  int i = blockIdx.x * blockDim.x + threadIdx.x;
  if (i < 64000) outu[6400 + i] = INF_BITS;
  if (i < 32768) xTpad[i] = (u32x4){0u, 0u, 0u, 0u};  // rows 6272..6399 of xT
  if (i < 128) x2u[6272 + i] = INF_BITS;
}

// ---- protos (2000x2048 f32) -> pT (2048x2048 bf16, pad rows zero) + p2 ----
__global__ __launch_bounds__(256) void k_prep_p(const float* __restrict__ protos,
                                                unsigned short* __restrict__ pT,
                                                float* __restrict__ p2) {
  const int row = blockIdx.x;   // 2048
  const int tid = threadIdx.x;  // 256
  __shared__ float red[4];
  float s = 0.f;
  u16x8 h = (u16x8){0, 0, 0, 0, 0, 0, 0, 0};
  if (row < 2000) {
    const float* src = protos + (size_t)row * 2048 + tid * 8;
    f32x4 a = *(const f32x4*)src;
    f32x4 c = *(const f32x4*)(src + 4);
    h = (u16x8){f2bf(a.x), f2bf(a.y), f2bf(a.z), f2bf(a.w),
                f2bf(c.x), f2bf(c.y), f2bf(c.z), f2bf(c.w)};
    s = a.x * a.x + a.y * a.y + a.z * a.z + a.w * a.w +
        c.x * c.x + c.y * c.y + c.z * c.z + c.w * c.w;
  }
  *(u16x8*)(pT + (size_t)row * 2048 + tid * 8) = h;
  #pragma unroll
  for (int off = 32; off; off >>= 1) s += __shfl_xor(s, off);
  if ((tid & 63) == 0) red[tid >> 6] = s;
  __syncthreads();
  if (tid == 0) p2[row] = red[0] + red[1] + red[2] + red[3];
}

// ---- x (b,k,n) f32 -> xT[(b*196+n)*2048+k] bf16 + x2 partials ----
__global__ __launch_bounds__(256) void k_prep_x(const float* __restrict__ x,
                                                unsigned short* __restrict__ xT,
                                                float* __restrict__ x2p) {
  const int kt = blockIdx.x;  // 32
  const int b  = blockIdx.y;  // 32
  const int tid = threadIdx.x;
  __shared__ unsigned short Ls[64][201];
  const float* src = x + ((size_t)b * 2048 + (size_t)kt * 64) * 196;
  for (int idx = tid; idx < 64 * 196; idx += 256) {
    int kk = idx / 196, n = idx - kk * 196;
    Ls[kk][n] = f2bf(src[idx]);
  }
  __syncthreads();
  if (tid < 196) {  // x2 partial from bf16 values (column tid)
    float s = 0.f;
    #pragma unroll
    for (int j = 0; j < 64; ++j) {
      float v = __uint_as_float((unsigned int)Ls[j][tid] << 16);
      s += v * v;
    }
    x2p[kt * 6272 + b * 196 + tid] = s;
  }
  unsigned short* dstb = xT + (size_t)b * 196 * 2048 + kt * 64;
  for (int idx = tid; idx < 196 * 32; idx += 256) {
    int n = idx >> 5, j = idx & 31;
    unsigned int v = (unsigned int)Ls[2 * j][n] |
                     ((unsigned int)Ls[2 * j + 1][n] << 16);
    *(unsigned int*)(dstb + (size_t)n * 2048 + 2 * j) = v;
  }
}

__global__ void k_x2r(const float* __restrict__ x2p, float* __restrict__ x2) {
  int i = blockIdx.x * blockDim.x + threadIdx.x;
  if (i >= 6272) return;
  float s = 0.f;
  #pragma unroll
  for (int c = 0; c < 32; ++c) s += x2p[c * 6272 + i];
  x2[i] = s;
}

// ---- main GEMM: 256x256, BK=64, 8 waves; unpinned interior, 2 barriers/K-tile ----
__global__ __launch_bounds__(512, 2) void k_main(
    const unsigned short* __restrict__ pT, const unsigned short* __restrict__ xT,
    const float* __restrict__ p2, const float* __restrict__ x2,
    unsigned int* __restrict__ outu) {
  // XCD swizzle: XCD x owns wgid [25x, 25x+25) = 2 ptiles x ~12.5 mtiles
  const int orig = blockIdx.x;
  const int wgid = (orig & 7) * 25 + (orig >> 3);
  const int ptpair = wgid / 50;
  const int rem = wgid - ptpair * 50;
  const int ptile = ptpair * 2 + (rem & 1);  // 0..7
  const int mtile = rem >> 1;                // 0..24
  const int p0 = ptile * 256;
  const int m0 = mtile * 256;
  const int tid = threadIdx.x;
  const int lane = tid & 63;
  const int w = tid >> 6;   // 8 waves
  const int wp = w >> 2;    // A half (128 rows)
  const int wn = w & 3;     // B quarter (64 rows)
  const int lr = lane & 15;
  const int lg = lane >> 4;

  __shared__ __align__(16) char S[131072];  // A[2]:0..64K, B[2]:64K..128K

  f32x4 acc[8][4];
  #pragma unroll
  for (int mi = 0; mi < 8; ++mi)
    #pragma unroll
    for (int ni = 0; ni < 4; ++ni)
      acc[mi][ni] = (f32x4){0.f, 0.f, 0.f, 0.f};

  // staging: linear LDS dest, pre-swizzled global source (chunk ^= row&7)
  const int rowbase = tid >> 3;                       // 0..63
  const int chunk = (tid & 7) ^ (rowbase & 7);        // involution
  const char* gA = (const char*)pT + (size_t)(p0 + rowbase) * 4096 + chunk * 16;
  const char* gB = (const char*)xT + (size_t)(m0 + rowbase) * 4096 + chunk * 16;
  const int wbase = w * 1024;

#define STAGE_A(c_, kt_, h_) do {                                              \
    const char* s_ = gA + (size_t)((h_) * 128 * 4096) + (size_t)(kt_) * 128;   \
    _Pragma("unroll")                                                          \
    for (int j_ = 0; j_ < 2; ++j_)                                             \
      __builtin_amdgcn_global_load_lds(                                        \
          (const AS1 void*)(s_ + (size_t)j_ * 64 * 4096),                      \
          (AS3 void*)(S + (c_) * 32768 + (h_) * 16384 + j_ * 8192 + wbase),    \
          16, 0, 0);                                                           \
  } while (0)
#define STAGE_B(c_, kt_, h_) do {                                              \
    const char* s_ = gB + (size_t)((h_) * 128 * 4096) + (size_t)(kt_) * 128;   \
    _Pragma("unroll")                                                          \
    for (int j_ = 0; j_ < 2; ++j_)                                             \
      __builtin_amdgcn_global_load_lds(                                        \
          (const AS1 void*)(s_ + (size_t)j_ * 64 * 4096),                      \
          (AS3 void*)(S + 65536 + (c_) * 32768 + (h_) * 16384 + j_ * 8192 + wbase), \
          16, 0, 0);                                                           \
  } while (0)
#define STAGE_FULL(c_, kt_) do {                                               \
    STAGE_A(c_, kt_, 0); STAGE_A(c_, kt_, 1);                                  \
    STAGE_B(c_, kt_, 0); STAGE_B(c_, kt_, 1); } while (0)

  // ds_read fragment addressing (row&7 == lr&7 since all row steps are x16)
  const int swz = ((lr & 7) << 4);
  const int arow = (wp * 128 + lr) * 128;        // + (mi>>2)*8192 + (mi&3)*2048
  const int brow = (wn * 64 + lr) * 128;         // + ni*2048 (B region +65536)
  const int koff0 = (lg * 16) ^ swz;
  const int koff1 = (64 + lg * 16) ^ swz;

#define READ_A8(dst_, c_, ko_)                                                 \
    _Pragma("unroll")                                                          \
    for (int mi_ = 0; mi_ < 8; ++mi_)                                          \
      dst_[mi_] = *(const bf16x8*)(S + (c_) * 32768 + arow + (mi_ >> 2) * 8192 \
                                   + (mi_ & 3) * 2048 + (ko_));
#define READ_B4(dst_, c_, ko_)                                                 \
    _Pragma("unroll")                                                          \
    for (int ni_ = 0; ni_ < 4; ++ni_)                                          \
      dst_[ni_] = *(const bf16x8*)(S + 65536 + (c_) * 32768 + brow +           \
                                   ni_ * 2048 + (ko_));
#define MFMA_ALL(af_, bf_)                                                     \
    _Pragma("unroll")                                                          \
    for (int mi_ = 0; mi_ < 8; ++mi_)                                          \
      _Pragma("unroll")                                                        \
      for (int ni_ = 0; ni_ < 4; ++ni_)                                        \
        acc[mi_][ni_] = __builtin_amdgcn_mfma_f32_16x16x32_bf16(               \
            af_[mi_], bf_[ni_], acc[mi_][ni_], 0, 0, 0);

#define SBAR() do { __builtin_amdgcn_sched_barrier(0);                         \
    __builtin_amdgcn_s_barrier(); __builtin_amdgcn_sched_barrier(0); } while (0)

  // Per K-tile kt (buf c):
  //   [arrival bar from prev iter: buf c data visible]
  //   interior: 24 ds_reads + 64 MFMA, UNPINNED (compiler interleaves pipes)
  //   lgkm0; release bar (all waves done reading c)
  //   vmcnt(0) (retires kt+1's loads, issued 1 K-tile ago -> ~free)
  //   stage kt+2 -> c ; arrival bar
#define KT_BODY(kt_, c_, sa_, tail_) do {                                      \
    {                                                                          \
      bf16x8 a8[8], bb[4];                                                     \
      READ_A8(a8, c_, koff0);                                                  \
      READ_B4(bb, c_, koff0);                                                  \
      MFMA_ALL(a8, bb);                                                        \
    }                                                                          \
    {                                                                          \
      bf16x8 a8[8], bb[4];                                                     \
      READ_A8(a8, c_, koff1);                                                  \
      READ_B4(bb, c_, koff1);                                                  \
      MFMA_ALL(a8, bb);                                                        \
    }                                                                          \
    if (!(tail_)) {                                                            \
      asm volatile("s_waitcnt lgkmcnt(0)" ::: "memory");                       \
      SBAR(); /* release buf c */                                              \
      asm volatile("s_waitcnt vmcnt(0)" ::: "memory");                         \
      __builtin_amdgcn_sched_barrier(0);                                       \
      if (sa_) STAGE_FULL(c_, (kt_) + 2);                                      \
      SBAR(); /* arrival buf c^1 */                                            \
    }                                                                          \
  } while (0)

  // prologue: kt0 -> buf0, kt1 -> buf1 (16 loads); wait kt0's 8; sync
  STAGE_FULL(0, 0);
  STAGE_FULL(1, 1);
  asm volatile("s_waitcnt vmcnt(8)" ::: "memory");
  __builtin_amdgcn_sched_barrier(0);
  __builtin_amdgcn_s_barrier();
  __builtin_amdgcn_sched_barrier(0);

  #pragma unroll 1
  for (int it = 0; it < 15; ++it) {
    KT_BODY(2 * it, 0, 1, 0);
    KT_BODY(2 * it + 1, 1, 1, 0);
  }
  KT_BODY(30, 0, 0, 0);  // no stage; vmcnt(0) retires kt31's loads
  KT_BODY(31, 1, 0, 1);  // pure compute, no trailing sync
#undef KT_BODY
#undef MFMA_ALL
#undef READ_A8
#undef READ_B4
#undef STAGE_FULL
#undef STAGE_A
#undef STAGE_B

  // epilogue: d2 = x2[m] + p2[p] - 2*dot ; per-wave 64-col window, <=2 batches
  const int wm_base = m0 + wn * 64;
  const int b_lo = wm_base / 196;
  int b_hi = (wm_base + 63) / 196;
  if (b_hi > 31) b_hi = 31;
  const bool wave_ok = (b_lo < 32);
  float x2v[4];
  int seg0[4];
  #pragma unroll
  for (int ni = 0; ni < 4; ++ni) {
    const int m = wm_base + ni * 16 + lr;  // D col = lane&15
    x2v[ni] = x2[m];
    seg0[ni] = ((m / 196) == b_lo);
  }
  const float INF = __uint_as_float(INF_BITS);
  #pragma unroll
  for (int mi = 0; mi < 8; ++mi) {
    const int prow = p0 + wp * 128 + mi * 16 + 4 * lg;  // D row = 4*(lane>>4)+j
    #pragma unroll
    for (int j = 0; j < 4; ++j) {
      const int p = prow + j;
      const float pp = p2[p];
      float ma = INF, mb = INF;
      #pragma unroll
      for (int ni = 0; ni < 4; ++ni) {
        const float d2 = x2v[ni] + pp - 2.f * acc[mi][ni][j];
        ma = fminf(ma, seg0[ni] ? d2 : INF);
        mb = fminf(mb, seg0[ni] ? INF : d2);
      }
      #pragma unroll
      for (int off = 1; off < 16; off <<= 1) {
        ma = fminf(ma, __shfl_xor(ma, off));
        mb = fminf(mb, __shfl_xor(mb, off));
      }
      if (lr == 0 && p < 2000 && wave_ok) {
        atomicMin(&outu[6400 + b_lo * 2000 + p], __float_as_uint(fmaxf(ma, 0.f)));
        if (b_hi != b_lo)
          atomicMin(&outu[6400 + b_hi * 2000 + p], __float_as_uint(fmaxf(mb, 0.f)));
      }
    }
  }
}

// ---- post: d = sqrt(max(d2,1e-12)) in place; sim -> simbuf ----
__global__ void k_post(float* __restrict__ out, float* __restrict__ simbuf) {
  int i = blockIdx.x * blockDim.x + threadIdx.x;
  if (i >= 64000) return;
  float d2 = out[6400 + i];
  float d = sqrtf(fmaxf(d2, 1e-12f));
  out[6400 + i] = d;
  simbuf[i] = logf((d + 1.0f) / (d + 1e-7f));
}

// ---- scores: one wave per (b, class) pair ----
__global__ __launch_bounds__(256) void k_scores(const float* __restrict__ fc_w,
                                                const float* __restrict__ simbuf,
                                                float* __restrict__ out) {
  const int id = blockIdx.x * 4 + (threadIdx.x >> 6);  // 0..6399
  const int lane = threadIdx.x & 63;
  const int b = id / 200;
  const int c = id - b * 200;
  const f32x4* sv = (const f32x4*)(simbuf + (size_t)b * 2000);
  const f32x4* wv = (const f32x4*)(fc_w + (size_t)c * 2000);
  float s = 0.f;
  #pragma unroll
  for (int it = 0; it < 8; ++it) {
    int i = lane + it * 64;
    if (i < 500) {
      f32x4 a = sv[i], w4 = wv[i];
      s += a.x * w4.x + a.y * w4.y + a.z * w4.z + a.w * w4.w;
    }
  }
  #pragma unroll
  for (int off = 32; off; off >>= 1) s += __shfl_xor(s, off);
  if (lane == 0) out[b * 200 + c] = s;
}

extern "C" void kernel_launch(void* const* d_in, const int* in_sizes, int n_in,
                              void* d_out, int out_size, void* d_ws, size_t ws_size,
                              hipStream_t stream) {
  const float* x      = (const float*)d_in[0];  // (32, 2048, 14, 14) f32
  const float* protos = (const float*)d_in[1];  // (1, 2000, 2048) f32
  const float* fc_w   = (const float*)d_in[2];  // (200, 2000) f32
  float* out = (float*)d_out;                   // 6400 scores + 64000 min-dists

  char* wsb = (char*)d_ws;
  unsigned short* pT = (unsigned short*)wsb;              // 2048*4096B  = 8388608
  unsigned short* xT = (unsigned short*)(wsb + 8388608);  // 6400*4096B  = 26214400
  float* p2   = (float*)(wsb + 34603008);                 // 2048 f32
  float* x2   = (float*)(wsb + 34611200);                 // 6400 f32 (pad +inf)
  float* x2p  = (float*)(wsb + 34636800);                 // 32*6272 f32
  float* simb = (float*)(wsb + 34636800);                 // aliases x2p (used later)

  k_init<<<256, 256, 0, stream>>>((unsigned int*)d_out,
                                  (u32x4*)(wsb + 8388608 + (size_t)6272 * 4096),
                                  (unsigned int*)x2);
  k_prep_p<<<2048, 256, 0, stream>>>(protos, pT, p2);
  k_prep_x<<<dim3(32, 32), 256, 0, stream>>>(x, xT, x2p);
  k_x2r<<<25, 256, 0, stream>>>(x2p, x2);
  k_main<<<200, 512, 0, stream>>>(pT, xT, p2, x2, (unsigned int*)d_out);
  k_post<<<250, 256, 0, stream>>>(out, simb);
  k_scores<<<1600, 256, 0, stream>>>(fc_w, simb, out);
}